// Round 3
// baseline (337.145 us; speedup 1.0000x reference)
//
#include <hip/hip_runtime.h>
#include <hip/hip_bf16.h>
#include <cstdint>
#include <cstddef>

// Problem constants (fixed by reference)
#define BROWS   16384
#define LDIM    128
#define HDIM    512
#define KDIM    1152            // LABEL_DIM + 2*H_DIM
#define NGATES  2560            // 5 * HDIM  (i, o, u, f0, f1)
#define NKT32   36              // K-tiles of BK=32

// workspace layout (bytes)
#define XB_BYTES  ((size_t)BROWS * KDIM * 2)            // 37,748,736
#define WB_BYTES  ((size_t)NGATES * KDIM * 2)           //  5,898,240
// gates: BROWS * NGATES bf16 = 83,886,080

using f32x4   = __attribute__((ext_vector_type(4))) float;
using bfrag   = __attribute__((ext_vector_type(8))) short;   // 8 bf16 = 4 VGPRs

__device__ __forceinline__ short f2bf(float f) {
    union { float f; uint32_t u; } a; a.f = f;
    uint32_t u = a.u;
    uint32_t lsb = (u >> 16) & 1u;
    u += 0x7fffu + lsb;               // round-to-nearest-even
    return (short)(u >> 16);
}
__device__ __forceinline__ float bf2f(short s) {
    union { uint32_t u; float f; } a;
    a.u = ((uint32_t)(uint16_t)s) << 16;
    return a.f;
}

__device__ __forceinline__ void load_lds16(const void* g, void* l) {
    __builtin_amdgcn_global_load_lds(
        (const __attribute__((address_space(1))) void*)g,
        (__attribute__((address_space(3))) void*)l, 16, 0, 0);
}

__device__ __forceinline__ float fast_sigmoid(float x) {
    return 1.0f / (1.0f + __expf(-x));
}
__device__ __forceinline__ float fast_tanh(float x) {
    float t = __expf(2.0f * x);
    return 1.0f - 2.0f / (t + 1.0f);
}

// ---------------------------------------------------------------------------
// pack_all: one launch.
//   blocks [0, NBX): xb[b, :] = bf16([label[b,:] | h0[b,:] | h1[b,:]])
//   blocks [NBX, NBX+NBW): Wb row n = bf16 of the gate-n weight row
// 8 elements per thread: 2x float4 load -> 1x 16B bf16 store.
// ---------------------------------------------------------------------------
#define NBX  ((BROWS  * (KDIM / 8)) / 256)   // 9216
#define NBW  ((NGATES * (KDIM / 8)) / 256)   // 1440

__global__ __launch_bounds__(256) void pack_all(
    const float* __restrict__ label, const float* __restrict__ chh,
    const float* __restrict__ Wi, const float* __restrict__ Wo,
    const float* __restrict__ Wu, const float* __restrict__ Wfl,
    const float* __restrict__ Wfs,
    short* __restrict__ xb, short* __restrict__ Wb)
{
    const int perRow = KDIM / 8;  // 144
    int blk = blockIdx.x;
    const float* src;
    short* dst;
    if (blk < NBX) {
        int tid = blk * 256 + threadIdx.x;
        int b = tid / perRow;
        int d = (tid - b * perRow) * 8;
        if (d < LDIM) {
            src = label + (size_t)b * LDIM + d;
        } else {
            int dd = d - LDIM;
            int k  = dd >> 9;
            int j  = dd & 511;
            src = chh + ((size_t)k * BROWS + b) * HDIM + j;
        }
        dst = xb + (size_t)b * KDIM + d;
    } else {
        int tid = (blk - NBX) * 256 + threadIdx.x;
        int n = tid / perRow;
        int d = (tid - n * perRow) * 8;
        int g = n >> 9, h = n & 511;
        if (g == 0)      src = Wi + (size_t)h * KDIM + d;
        else if (g == 1) src = Wo + (size_t)h * KDIM + d;
        else if (g == 2) src = Wu + (size_t)h * KDIM + d;
        else {
            int k = g - 3;
            if (d < LDIM) {
                src = Wfl + (size_t)h * LDIM + d;
            } else {
                int dd = d - LDIM;
                int j  = dd >> 9;
                int jj = dd & 511;
                src = Wfs + (((size_t)(k * 2 + j) * HDIM + h) * HDIM) + jj;
            }
        }
        dst = Wb + (size_t)n * KDIM + d;
    }
    float4 v0 = *(const float4*)src;
    float4 v1 = *(const float4*)(src + 4);
    bfrag s;
    s[0] = f2bf(v0.x); s[1] = f2bf(v0.y); s[2] = f2bf(v0.z); s[3] = f2bf(v0.w);
    s[4] = f2bf(v1.x); s[5] = f2bf(v1.y); s[6] = f2bf(v1.z); s[7] = f2bf(v1.w);
    *(bfrag*)dst = s;
}

// ---------------------------------------------------------------------------
// gemm_bt: 256x256 tile, BK=32, 8 waves (2Mx4N), TRIPLE-buffered LDS,
// ONE barrier per K-tile.
//
// Round-2 post-mortem: per-phase barriers locked the 8 waves into
// LDS-storm-then-MFMA alternation (measured 1417 cyc/phase = serial sum of
// the two pipes). This version gives the compiler a 12-ds_read + 32-MFMA
// barrier-free region per K-tile so ds_reads stream under MFMAs
// (fine-grained lgkmcnt), and B-frags are read ONCE per wave per tile
// (LDS traffic -25%).
//
// LDS: 3 buffers x (A 16 KB + B 16 KB) = 96 KiB. Buffer for tile t = t%3.
// Staging: 4 DMAs/tile (2 A halves + 2 B halves, 8 KB each, 16 B/thread).
// Depth-2 prefetch: tile t stages t+2 into buf[(t+2)%3] — that buffer's
// last reads were tile t-1, completed before barrier(t-1), and the stage
// is issued after it: legal with one barrier/tile.
// vmcnt discipline: tile-end vmcnt(4) confirms stage(t+1) (issued one full
// tile ~1500 cyc earlier => free) while stage(t+2)'s 4 DMAs stay in flight
// across the barrier. Never vmcnt(0) in steady state (single vmcnt(0) at
// t=34 drains loads issued 2 tiles prior).
//
// Swizzle (64 B rows, 4 slots of 16 B): staging thread t covers row sr=t>>2,
// physical slot t&3, sourced from global k-seg (t&3)^(sr&3); read of row r,
// k-seg q at byte r*64 + ((q^(r&3))<<4). Bank math: (l16&1, q^(l16&3))
// spans all 8 4-bank groups with 8 lanes each -> conflict-free (8 cyc/read).
// ---------------------------------------------------------------------------
__global__ __launch_bounds__(512, 2) void gemm_bt(const short* __restrict__ A,
                                                  const short* __restrict__ Bt,
                                                  short* __restrict__ C) {
    __shared__ short As[3][8192];   // 3 x 16 KB
    __shared__ short Bs[3][8192];   // 3 x 16 KB

    const int t    = threadIdx.x;
    const int lane = t & 63;
    const int wave = t >> 6;          // 0..7
    const int wr   = wave >> 2;       // 0..1  (M)
    const int wc   = wave & 3;        // 0..3  (N)
    const int quad = lane >> 4;       // 0..3
    const int l16  = lane & 15;

    // T1 (n-fastest): XCD c = bid&7 gets m-tiles [8c, 8c+8) x all 10 n-tiles,
    // n fastest. Concurrent 32 blocks/XCD share ~4 A-panels (L2-hot) + all B.
    const int local = blockIdx.x >> 3;           // 0..79
    const int mT    = (blockIdx.x & 7) * 8 + local / 10;
    const int nT    = local % 10;
    const int mBase = mT * 256;
    const int nBase = nT * 256;

    f32x4 acc[8][4] = {};

    // ---- staging constants: thread t -> row sr = t>>2 (0..127, +128 per
    // DMA-half d), physical 16B slot t&3, global k-seg (t&3)^(sr&3).
    const int sr  = t >> 2;
    const int ssl = (t & 3) ^ (sr & 3);
    const short* aSrc = A  + (size_t)(mBase + sr) * KDIM + ssl * 8;
    const short* bSrc = Bt + (size_t)(nBase + sr) * KDIM + ssl * 8;
    short* aDst = &As[0][0] + t * 8;      // lane-linear LDS dest
    short* bDst = &Bs[0][0] + t * 8;

#define STAGE_A(d, kt, buf) load_lds16(aSrc + (size_t)(d) * (128 * KDIM) + (kt) * 32, \
                                       aDst + (buf) * 8192 + (d) * 4096)
#define STAGE_B(d, kt, buf) load_lds16(bSrc + (size_t)(d) * (128 * KDIM) + (kt) * 32, \
                                       bDst + (buf) * 8192 + (d) * 4096)

    // ---- fragment-read constants. All of a thread's fragment rows have
    // row&3 == l16&3, so the swizzled k-slot is per-thread constant.
    const int kswz  = (quad ^ (l16 & 3)) << 4;
    const int aRowB = (wr * 128 + l16) * 64;   // byte offset of row in buffer
    const int bRowB = (wc * 64  + l16) * 64;

    // A frag i (0..7): rows wr*128 + i*16 + l16.  B frag j (0..3): wc*64+j*16+l16.
#define DS_A(buf, i) (*(const bfrag*)((const char*)(&As[0][0]) + (buf) * 16384 + aRowB + (i) * 1024 + kswz))
#define DS_B(buf, j) (*(const bfrag*)((const char*)(&Bs[0][0]) + (buf) * 16384 + bRowB + (j) * 1024 + kswz))

#define MM(af, bfr, i, j) acc[i][j] = \
    __builtin_amdgcn_mfma_f32_16x16x32_bf16(af, bfr, acc[i][j], 0, 0, 0)

// One K-tile: stage t+2 (guarded), 12 ds_read, 32 MFMA, counted vmcnt,
// single barrier. No lgkm drain — compiler schedules reads under MFMAs.
#define TILE(bufc, bufs, kt, doStage, vmZero) do { \
    if (doStage) { STAGE_A(0, (kt) + 2, bufs); STAGE_A(1, (kt) + 2, bufs); \
                   STAGE_B(0, (kt) + 2, bufs); STAGE_B(1, (kt) + 2, bufs); } \
    bfrag bb[4], aa[8]; \
    bb[0] = DS_B(bufc, 0); bb[1] = DS_B(bufc, 1); \
    bb[2] = DS_B(bufc, 2); bb[3] = DS_B(bufc, 3); \
    aa[0] = DS_A(bufc, 0); aa[1] = DS_A(bufc, 1); \
    aa[2] = DS_A(bufc, 2); aa[3] = DS_A(bufc, 3); \
    aa[4] = DS_A(bufc, 4); aa[5] = DS_A(bufc, 5); \
    aa[6] = DS_A(bufc, 6); aa[7] = DS_A(bufc, 7); \
    __builtin_amdgcn_s_setprio(1); \
    _Pragma("unroll") \
    for (int i = 0; i < 8; ++i) { \
        _Pragma("unroll") \
        for (int j = 0; j < 4; ++j) MM(aa[i], bb[j], i, j); \
    } \
    __builtin_amdgcn_s_setprio(0); \
    if (vmZero) { asm volatile("s_waitcnt vmcnt(0)" ::: "memory"); } \
    else        { asm volatile("s_waitcnt vmcnt(4)" ::: "memory"); } \
    __builtin_amdgcn_s_barrier(); \
} while (0)

    // ---- prologue: stage tile0 -> buf0, tile1 -> buf1; wait tile0 only.
    STAGE_A(0, 0, 0); STAGE_A(1, 0, 0); STAGE_B(0, 0, 0); STAGE_B(1, 0, 0);
    STAGE_A(0, 1, 1); STAGE_A(1, 1, 1); STAGE_B(0, 1, 1); STAGE_B(1, 1, 1);
    asm volatile("s_waitcnt vmcnt(4)" ::: "memory");
    __builtin_amdgcn_s_barrier();

#pragma unroll 1
    for (int k3 = 0; k3 < NKT32 / 3; ++k3) {
        const int kt = k3 * 3;
        TILE(0, 2, kt,     kt + 2 <= NKT32 - 1, false);
        TILE(1, 0, kt + 1, kt + 3 <= NKT32 - 1, kt + 1 == NKT32 - 2);
        TILE(2, 1, kt + 2, kt + 4 <= NKT32 - 1, kt + 2 == NKT32 - 2);
    }

    // ---- epilogue: C[m,n] bf16; C/D layout col=lane&15, row=(lane>>4)*4+r
#pragma unroll
    for (int i = 0; i < 8; ++i) {
        const int row0 = mBase + wr * 128 + i * 16 + quad * 4;
#pragma unroll
        for (int j = 0; j < 4; ++j) {
            const int col = nBase + wc * 64 + j * 16 + l16;
#pragma unroll
            for (int r = 0; r < 4; ++r) {
                C[(size_t)(row0 + r) * NGATES + col] = f2bf(acc[i][j][r]);
            }
        }
    }
#undef TILE
#undef MM
#undef DS_A
#undef DS_B
#undef STAGE_A
#undef STAGE_B
}

// ---------------------------------------------------------------------------
// epilogue: gates (B x 2560 bf16 logits) -> next_cell, out (fp32).
// 8 h-columns per thread: each gate read is one 16B bfrag, chc/out via float4.
// ---------------------------------------------------------------------------
__global__ __launch_bounds__(256) void epilogue(const short* __restrict__ gates,
                                                const float* __restrict__ chc,
                                                const float* __restrict__ b_i,
                                                const float* __restrict__ b_o,
                                                const float* __restrict__ b_u,
                                                const float* __restrict__ fbias,
                                                float* __restrict__ out) {
    int tid = blockIdx.x * 256 + threadIdx.x;     // over B * (H/8)
    int b  = tid >> 6;                            // H/8 = 64 per row
    int h8 = (tid & 63) << 3;

    const short* g = gates + (size_t)b * NGATES + h8;
    bfrag vi  = *(const bfrag*)(g);
    bfrag vo  = *(const bfrag*)(g + HDIM);
    bfrag vu  = *(const bfrag*)(g + 2 * HDIM);
    bfrag vf0 = *(const bfrag*)(g + 3 * HDIM);
    bfrag vf1 = *(const bfrag*)(g + 4 * HDIM);

    float4 bi0 = *(const float4*)(b_i + h8),   bi1 = *(const float4*)(b_i + h8 + 4);
    float4 bo0 = *(const float4*)(b_o + h8),   bo1 = *(const float4*)(b_o + h8 + 4);
    float4 bu0 = *(const float4*)(b_u + h8),   bu1 = *(const float4*)(b_u + h8 + 4);
    float4 fb0 = *(const float4*)(fbias + h8), fb1 = *(const float4*)(fbias + h8 + 4);

    size_t cbase = (size_t)b * HDIM + h8;
    float4 c00 = *(const float4*)(chc + cbase);
    float4 c01 = *(const float4*)(chc + cbase + 4);
    float4 c10 = *(const float4*)(chc + (size_t)BROWS * HDIM + cbase);
    float4 c11 = *(const float4*)(chc + (size_t)BROWS * HDIM + cbase + 4);

    float bi[8] = {bi0.x,bi0.y,bi0.z,bi0.w, bi1.x,bi1.y,bi1.z,bi1.w};
    float bo[8] = {bo0.x,bo0.y,bo0.z,bo0.w, bo1.x,bo1.y,bo1.z,bo1.w};
    float bu[8] = {bu0.x,bu0.y,bu0.z,bu0.w, bu1.x,bu1.y,bu1.z,bu1.w};
    float fb[8] = {fb0.x,fb0.y,fb0.z,fb0.w, fb1.x,fb1.y,fb1.z,fb1.w};
    float c0[8] = {c00.x,c00.y,c00.z,c00.w, c01.x,c01.y,c01.z,c01.w};
    float c1[8] = {c10.x,c10.y,c10.z,c10.w, c11.x,c11.y,c11.z,c11.w};

    float nc[8], ou[8];
#pragma unroll
    for (int e = 0; e < 8; ++e) {
        float ig = fast_sigmoid(bf2f(vi[e]) + bi[e]);
        float og = fast_sigmoid(bf2f(vo[e]) + bo[e]);
        float uu = fast_tanh(bf2f(vu[e]) + bu[e]);
        float f0 = fast_sigmoid(bf2f(vf0[e]));
        float f1 = fast_sigmoid(bf2f(vf1[e]));
        float ncell = ig * uu + f0 * c0[e] + f1 * c1[e] + fb[e] * (c0[e] + c1[e]);
        nc[e] = ncell;
        ou[e] = fast_tanh(og * ncell);
    }
    float4 n0 = {nc[0], nc[1], nc[2], nc[3]}, n1 = {nc[4], nc[5], nc[6], nc[7]};
    float4 o0 = {ou[0], ou[1], ou[2], ou[3]}, o1 = {ou[4], ou[5], ou[6], ou[7]};
    *(float4*)(out + cbase)     = n0;
    *(float4*)(out + cbase + 4) = n1;
    *(float4*)(out + (size_t)BROWS * HDIM + cbase)     = o0;
    *(float4*)(out + (size_t)BROWS * HDIM + cbase + 4) = o1;
}

// ---------------------------------------------------------------------------
extern "C" void kernel_launch(void* const* d_in, const int* in_sizes, int n_in,
                              void* d_out, int out_size, void* d_ws, size_t ws_size,
                              hipStream_t stream) {
    const float* label = (const float*)d_in[0];
    const float* chh   = (const float*)d_in[1];
    const float* chc   = (const float*)d_in[2];
    const float* W_i   = (const float*)d_in[3];
    const float* b_i   = (const float*)d_in[4];
    const float* W_o   = (const float*)d_in[5];
    const float* b_o   = (const float*)d_in[6];
    const float* W_u   = (const float*)d_in[7];
    const float* b_u   = (const float*)d_in[8];
    const float* W_fl  = (const float*)d_in[9];
    const float* W_fs  = (const float*)d_in[10];
    const float* fbias = (const float*)d_in[11];
    float* out = (float*)d_out;

    char* ws = (char*)d_ws;
    short* xb    = (short*)ws;                          // B x K bf16
    short* Wb    = (short*)(ws + XB_BYTES);             // 2560 x K bf16
    short* gates = (short*)(ws + XB_BYTES + WB_BYTES);  // B x 2560 bf16

    pack_all<<<NBX + NBW, 256, 0, stream>>>(label, chh, W_i, W_o, W_u, W_fl, W_fs, xb, Wb);

    // 256x256 tiles: (16384/256) x (2560/256) = 64 x 10 = 640 blocks, 512 thr
    gemm_bt<<<dim3(640), 512, 0, stream>>>(xb, Wb, gates);

    epilogue<<<(BROWS * (HDIM / 8)) / 256, 256, 0, stream>>>(gates, chc, b_i, b_o, b_u, fbias, out);
}

// Round 4
// 295.722 us; speedup vs baseline: 1.1401x; 1.1401x over previous
//
#include <hip/hip_runtime.h>
#include <hip/hip_bf16.h>
#include <cstdint>
#include <cstddef>

// Problem constants (fixed by reference)
#define BROWS   16384
#define LDIM    128
#define HDIM    512
#define KDIM    1152            // LABEL_DIM + 2*H_DIM
#define NGATES  2560            // 5 * HDIM  (i, o, u, f0, f1)
#define NKT     (KDIM / 64)     // 18 K-tiles of BK=64

// workspace layout (bytes)
#define XB_BYTES  ((size_t)BROWS * KDIM * 2)            // 37,748,736
#define WB_BYTES  ((size_t)NGATES * KDIM * 2)           //  5,898,240

using f32x4   = __attribute__((ext_vector_type(4))) float;
using bfrag   = __attribute__((ext_vector_type(8))) short;   // 8 bf16 = 4 VGPRs

__device__ __forceinline__ short f2bf(float f) {
    union { float f; uint32_t u; } a; a.f = f;
    uint32_t u = a.u;
    uint32_t lsb = (u >> 16) & 1u;
    u += 0x7fffu + lsb;               // round-to-nearest-even
    return (short)(u >> 16);
}

__device__ __forceinline__ void load_lds16(const void* g, void* l) {
    __builtin_amdgcn_global_load_lds(
        (const __attribute__((address_space(1))) void*)g,
        (__attribute__((address_space(3))) void*)l, 16, 0, 0);
}

__device__ __forceinline__ float fast_sigmoid(float x) {
    return 1.0f / (1.0f + __expf(-x));
}
__device__ __forceinline__ float fast_tanh(float x) {
    float t = __expf(2.0f * x);
    return 1.0f - 2.0f / (t + 1.0f);
}

// ---------------------------------------------------------------------------
// pack_all: unchanged.
//   blocks [0, NBX): xb[b, :] = bf16([label[b,:] | h0[b,:] | h1[b,:]])
//   blocks [NBX, NBX+NBW): Wb row n = bf16 of the gate-n weight row
// ---------------------------------------------------------------------------
#define NBX  ((BROWS  * (KDIM / 8)) / 256)   // 9216
#define NBW  ((NGATES * (KDIM / 8)) / 256)   // 1440

__global__ __launch_bounds__(256) void pack_all(
    const float* __restrict__ label, const float* __restrict__ chh,
    const float* __restrict__ Wi, const float* __restrict__ Wo,
    const float* __restrict__ Wu, const float* __restrict__ Wfl,
    const float* __restrict__ Wfs,
    short* __restrict__ xb, short* __restrict__ Wb)
{
    const int perRow = KDIM / 8;  // 144
    int blk = blockIdx.x;
    const float* src;
    short* dst;
    if (blk < NBX) {
        int tid = blk * 256 + threadIdx.x;
        int b = tid / perRow;
        int d = (tid - b * perRow) * 8;
        if (d < LDIM) {
            src = label + (size_t)b * LDIM + d;
        } else {
            int dd = d - LDIM;
            int k  = dd >> 9;
            int j  = dd & 511;
            src = chh + ((size_t)k * BROWS + b) * HDIM + j;
        }
        dst = xb + (size_t)b * KDIM + d;
    } else {
        int tid = (blk - NBX) * 256 + threadIdx.x;
        int n = tid / perRow;
        int d = (tid - n * perRow) * 8;
        int g = n >> 9, h = n & 511;
        if (g == 0)      src = Wi + (size_t)h * KDIM + d;
        else if (g == 1) src = Wo + (size_t)h * KDIM + d;
        else if (g == 2) src = Wu + (size_t)h * KDIM + d;
        else {
            int k = g - 3;
            if (d < LDIM) {
                src = Wfl + (size_t)h * LDIM + d;
            } else {
                int dd = d - LDIM;
                int j  = dd >> 9;
                int jj = dd & 511;
                src = Wfs + (((size_t)(k * 2 + j) * HDIM + h) * HDIM) + jj;
            }
        }
        dst = Wb + (size_t)n * KDIM + d;
    }
    float4 v0 = *(const float4*)src;
    float4 v1 = *(const float4*)(src + 4);
    bfrag s;
    s[0] = f2bf(v0.x); s[1] = f2bf(v0.y); s[2] = f2bf(v0.z); s[3] = f2bf(v0.w);
    s[4] = f2bf(v1.x); s[5] = f2bf(v1.y); s[6] = f2bf(v1.z); s[7] = f2bf(v1.w);
    *(bfrag*)dst = s;
}

// ---------------------------------------------------------------------------
// gemm_fused: 256(m) x 320(n) tile where the 320 columns are the SAME
// 64-wide h-strip of ALL FIVE gates (B rows gathered from Wb at
// g*512 + h0 + hh, g=0..4). Consequence: frag j == gate j, and every lane
// holds i,o,u,f0,f1 logits for identical (b, h = h0 + wc*16 + l16) — the
// LSTM epilogue is per-lane arithmetic fused after the K-loop. gates buffer
// and epilogue kernel are GONE; logits stay fp32 (more accurate).
//
// Grid: 64 m-tiles x 8 h-strips = 512 blocks = exactly 2.0 CU-rounds.
// Core: round-2 4-phase (mh,ks) schedule, one barrier/phase, proven 128B-row
// XOR swizzle (0 conflicts measured), 9 DMAs/K64-tile (A q0..q3 + B d0..d4),
// depth-2 A prefetch, steady-state s_waitcnt vmcnt(2) (never 0 mid-loop).
// DMA ledger at tile-end wait: this tile issued 9 (7 for kt+1, 2 = A(kt+2)
// q0/q2); A(kt+1)q0/q2 were the 2 left in flight by the PREVIOUS vmcnt(2),
// landed since. vmcnt(2) -> all of kt+1 resident, A(kt+2)q0/q2 in flight.
// Legality of same-buffer A(kt+2)q0/q2 stage: cur-buf q0/q2 last read in
// phases (0,*), done before the barrier that precedes phases (1,*).
// LDS: A 2x32 KB + B 2x40 KB = 144 KiB.
// ---------------------------------------------------------------------------
__global__ __launch_bounds__(512, 2) void gemm_fused(
    const short* __restrict__ A, const short* __restrict__ Wb,
    const float* __restrict__ chc,
    const float* __restrict__ b_i, const float* __restrict__ b_o,
    const float* __restrict__ b_u, const float* __restrict__ fbias,
    float* __restrict__ out)
{
    __shared__ short As[2][16384];   // 2 x 32 KB (256 rows x 128 B)
    __shared__ short Bs[2][20480];   // 2 x 40 KB (320 rows x 128 B)

    const int t    = threadIdx.x;
    const int lane = t & 63;
    const int wave = t >> 6;          // 0..7
    const int wr   = wave >> 2;       // 0..1  (M)
    const int wc   = wave & 3;        // 0..3  (N, 16-col group within h-strip)
    const int quad = lane >> 4;       // 0..3
    const int l16  = lane & 15;

    // XCD chunking (512 % 8 == 0, bijective): XCD c owns m-tiles [8c,8c+8),
    // h-strip fastest -> resident blocks share A-panels (L2-hot).
    const int local = blockIdx.x >> 3;            // 0..63
    const int mT    = (blockIdx.x & 7) * 8 + (local >> 3);
    const int nT    = local & 7;                  // h-strip
    const int mBase = mT * 256;
    const int h0    = nT * 64;

    f32x4 acc[8][5] = {};   // [m-frag][gate]

    // ---- staging: thread t -> row sr = t>>3 (0..63 per DMA), phys 16B slot
    // t&7, sourced from global k-seg (t&7)^(sr&7)  (proven 128B-row swizzle).
    const int sr  = t >> 3;
    const int ssl = (t & 7) ^ (sr & 7);
    const short* aSrc = A  + (size_t)(mBase + sr) * KDIM + ssl * 8;
    const short* bSrc = Wb + (size_t)(h0    + sr) * KDIM + ssl * 8;   // gate 0
    short* aDst = &As[0][0] + t * 8;      // lane-linear LDS dest
    short* bDst = &Bs[0][0] + t * 8;

    // A quarter q (64 rows), B strip d = gate d (rows g*512+h0+sr of Wb)
#define STAGE_A(q, kt, buf) load_lds16(aSrc + (size_t)(q) * (64 * KDIM) + (kt) * 64, \
                                       aDst + (buf) * 16384 + (q) * 4096)
#define STAGE_B(d, kt, buf) load_lds16(bSrc + (size_t)(d) * (512 * KDIM) + (kt) * 64, \
                                       bDst + (buf) * 20480 + (d) * 4096)

    // ---- fragment-read constants; all of a thread's rows have row&7==l16&7.
    const int kswz0 = ((quad)     ^ (l16 & 7)) << 4;   // ks=0
    const int kswz1 = ((quad + 4) ^ (l16 & 7)) << 4;   // ks=1
    const int aRowB = (wr * 128 + l16) << 7;           // byte offset of row
    const int bRowB = (wc * 16  + l16) << 7;

    // A frag (mh, i): rows wr*128 + mh*64 + i*16 + l16
#define DS_A(buf, mh, i, ks) (*(const bfrag*)((const char*)(&As[0][0]) + (buf) * 32768 + \
                              aRowB + (mh) * 8192 + (i) * 2048 + ((ks) ? kswz1 : kswz0)))
    // B frag g: rows g*64 + wc*16 + l16
#define DS_B(buf, g, ks) (*(const bfrag*)((const char*)(&Bs[0][0]) + (buf) * 40960 + \
                              (g) * 8192 + bRowB + ((ks) ? kswz1 : kswz0)))

#define MM(af, bfr, mi, g) acc[mi][g] = \
    __builtin_amdgcn_mfma_f32_16x16x32_bf16(af, bfr, acc[mi][g], 0, 0, 0)

// One phase (mh, ks): 9 ds_read_b128, prefetch issues, 20 MFMA. No lgkm
// drain — compiler pipelines reads under MFMAs; caller appends the barrier.
#define PHASE(buf, mh, ks, ...) do { \
    bfrag a0 = DS_A(buf, mh, 0, ks); \
    bfrag a1 = DS_A(buf, mh, 1, ks); \
    bfrag a2 = DS_A(buf, mh, 2, ks); \
    bfrag a3 = DS_A(buf, mh, 3, ks); \
    bfrag b0 = DS_B(buf, 0, ks); \
    bfrag b1 = DS_B(buf, 1, ks); \
    bfrag b2 = DS_B(buf, 2, ks); \
    bfrag b3 = DS_B(buf, 3, ks); \
    bfrag b4 = DS_B(buf, 4, ks); \
    __VA_ARGS__; \
    __builtin_amdgcn_s_setprio(1); \
    MM(a0, b0, (mh)*4+0, 0); MM(a0, b1, (mh)*4+0, 1); MM(a0, b2, (mh)*4+0, 2); \
    MM(a0, b3, (mh)*4+0, 3); MM(a0, b4, (mh)*4+0, 4); \
    MM(a1, b0, (mh)*4+1, 0); MM(a1, b1, (mh)*4+1, 1); MM(a1, b2, (mh)*4+1, 2); \
    MM(a1, b3, (mh)*4+1, 3); MM(a1, b4, (mh)*4+1, 4); \
    MM(a2, b0, (mh)*4+2, 0); MM(a2, b1, (mh)*4+2, 1); MM(a2, b2, (mh)*4+2, 2); \
    MM(a2, b3, (mh)*4+2, 3); MM(a2, b4, (mh)*4+2, 4); \
    MM(a3, b0, (mh)*4+3, 0); MM(a3, b1, (mh)*4+3, 1); MM(a3, b2, (mh)*4+3, 2); \
    MM(a3, b3, (mh)*4+3, 3); MM(a3, b4, (mh)*4+3, 4); \
    __builtin_amdgcn_s_setprio(0); \
} while (0)

    // ---- prologue: tile0 fully (9 DMAs) + A(1)q0/q2 -> 2 in flight at wait
    STAGE_A(0, 0, 0); STAGE_A(1, 0, 0); STAGE_A(2, 0, 0); STAGE_A(3, 0, 0);
    STAGE_B(0, 0, 0); STAGE_B(1, 0, 0); STAGE_B(2, 0, 0); STAGE_B(3, 0, 0);
    STAGE_B(4, 0, 0);
    STAGE_A(0, 1, 1); STAGE_A(2, 1, 1);
    asm volatile("s_waitcnt vmcnt(2)" ::: "memory");
    __builtin_amdgcn_s_barrier();

#pragma unroll 1
    for (int k2 = 0; k2 < NKT / 2; ++k2) {
        const int kt   = 2 * k2;
        const bool more = (k2 < NKT / 2 - 1);

        // ---- even K-tile kt (buf 0) ----
        PHASE(0, 0, 0, STAGE_A(1, kt + 1, 1); STAGE_B(0, kt + 1, 1); STAGE_B(1, kt + 1, 1));
        __builtin_amdgcn_s_barrier();
        PHASE(0, 0, 1, STAGE_A(3, kt + 1, 1); STAGE_B(2, kt + 1, 1); STAGE_B(3, kt + 1, 1));
        __builtin_amdgcn_s_barrier();
        PHASE(0, 1, 0, STAGE_B(4, kt + 1, 1); if (more) STAGE_A(0, kt + 2, 0));
        __builtin_amdgcn_s_barrier();
        PHASE(0, 1, 1, if (more) STAGE_A(2, kt + 2, 0));
        if (more) { asm volatile("s_waitcnt vmcnt(2)" ::: "memory"); }
        else      { asm volatile("s_waitcnt vmcnt(0)" ::: "memory"); }
        __builtin_amdgcn_s_barrier();

        // ---- odd K-tile kt+1 (buf 1) ----
        PHASE(1, 0, 0, if (more) { STAGE_A(1, kt + 2, 0); STAGE_B(0, kt + 2, 0); STAGE_B(1, kt + 2, 0); });
        __builtin_amdgcn_s_barrier();
        PHASE(1, 0, 1, if (more) { STAGE_A(3, kt + 2, 0); STAGE_B(2, kt + 2, 0); STAGE_B(3, kt + 2, 0); });
        __builtin_amdgcn_s_barrier();
        PHASE(1, 1, 0, if (more) { STAGE_B(4, kt + 2, 0); STAGE_A(0, kt + 3, 1); });
        __builtin_amdgcn_s_barrier();
        PHASE(1, 1, 1, if (more) STAGE_A(2, kt + 3, 1));
        if (more) { asm volatile("s_waitcnt vmcnt(2)" ::: "memory"); }
        else      { asm volatile("s_waitcnt vmcnt(0)" ::: "memory"); }
        __builtin_amdgcn_s_barrier();
    }

    // ---- fused LSTM epilogue. Lane holds all 5 gate logits (fp32) for
    // h = h0 + wc*16 + l16, rows b = mBase + wr*128 + mi*16 + quad*4 + r.
    // (acc[mh*4+i] <-> row offset mi*16: mh*64 + i*16 == (mh*4+i)*16.)
    const int h = h0 + wc * 16 + l16;
    const float bi = b_i[h], bo = b_o[h], bu = b_u[h], fb = fbias[h];
    const float* chc1 = chc + (size_t)BROWS * HDIM;
    float* out2 = out + (size_t)BROWS * HDIM;

#pragma unroll
    for (int mi = 0; mi < 8; ++mi) {
        const int row0 = mBase + wr * 128 + mi * 16 + quad * 4;
#pragma unroll
        for (int r = 0; r < 4; ++r) {
            const size_t idx = (size_t)(row0 + r) * HDIM + h;
            float ig = fast_sigmoid(acc[mi][0][r] + bi);
            float og = fast_sigmoid(acc[mi][1][r] + bo);
            float uu = fast_tanh(acc[mi][2][r] + bu);
            float f0 = fast_sigmoid(acc[mi][3][r]);
            float f1 = fast_sigmoid(acc[mi][4][r]);
            float c0 = chc[idx];
            float c1 = chc1[idx];
            float ncell = ig * uu + f0 * c0 + f1 * c1 + fb * (c0 + c1);
            out[idx]  = ncell;
            out2[idx] = fast_tanh(og * ncell);
        }
    }
#undef PHASE
#undef MM
#undef DS_A
#undef DS_B
#undef STAGE_A
#undef STAGE_B
}

// ---------------------------------------------------------------------------
extern "C" void kernel_launch(void* const* d_in, const int* in_sizes, int n_in,
                              void* d_out, int out_size, void* d_ws, size_t ws_size,
                              hipStream_t stream) {
    const float* label = (const float*)d_in[0];
    const float* chh   = (const float*)d_in[1];
    const float* chc   = (const float*)d_in[2];
    const float* W_i   = (const float*)d_in[3];
    const float* b_i   = (const float*)d_in[4];
    const float* W_o   = (const float*)d_in[5];
    const float* b_o   = (const float*)d_in[6];
    const float* W_u   = (const float*)d_in[7];
    const float* b_u   = (const float*)d_in[8];
    const float* W_fl  = (const float*)d_in[9];
    const float* W_fs  = (const float*)d_in[10];
    const float* fbias = (const float*)d_in[11];
    float* out = (float*)d_out;

    char* ws = (char*)d_ws;
    short* xb = (short*)ws;                    // B x K bf16
    short* Wb = (short*)(ws + XB_BYTES);       // 2560 x K bf16

    pack_all<<<NBX + NBW, 256, 0, stream>>>(label, chh, W_i, W_o, W_u, W_fl, W_fs, xb, Wb);

    // 64 m-tiles x 8 h-strips = 512 blocks (2.0 rounds of 256 CUs), 512 thr
    gemm_fused<<<dim3(512), 512, 0, stream>>>(xb, Wb, chc, b_i, b_o, b_u, fbias, out);
}

// Round 5
// 284.300 us; speedup vs baseline: 1.1859x; 1.0402x over previous
//
#include <hip/hip_runtime.h>
#include <hip/hip_bf16.h>
#include <cstdint>
#include <cstddef>

// Problem constants (fixed by reference)
#define BROWS   16384
#define LDIM    128
#define HDIM    512
#define KDIM    1152            // LABEL_DIM + 2*H_DIM
#define NGATES  2560            // 5 * HDIM  (i, o, u, f0, f1)
#define NKT     (KDIM / 64)     // 18 K-tiles of BK=64

// workspace layout (bytes)
#define XB_BYTES  ((size_t)BROWS * KDIM * 2)            // 37,748,736
#define WB_BYTES  ((size_t)NGATES * KDIM * 2)           //  5,898,240

using f32x4   = __attribute__((ext_vector_type(4))) float;
using bfrag   = __attribute__((ext_vector_type(8))) short;   // 8 bf16 = 4 VGPRs

__device__ __forceinline__ short f2bf(float f) {
    union { float f; uint32_t u; } a; a.f = f;
    uint32_t u = a.u;
    uint32_t lsb = (u >> 16) & 1u;
    u += 0x7fffu + lsb;               // round-to-nearest-even
    return (short)(u >> 16);
}

__device__ __forceinline__ void load_lds16(const void* g, void* l) {
    __builtin_amdgcn_global_load_lds(
        (const __attribute__((address_space(1))) void*)g,
        (__attribute__((address_space(3))) void*)l, 16, 0, 0);
}

__device__ __forceinline__ float fast_sigmoid(float x) {
    return 1.0f / (1.0f + __expf(-x));
}
__device__ __forceinline__ float fast_tanh(float x) {
    float t = __expf(2.0f * x);
    return 1.0f - 2.0f / (t + 1.0f);
}

// ---------------------------------------------------------------------------
// pack_all: unchanged (diagnostic control — see round-5 theory).
//   blocks [0, NBX): xb[b, :] = bf16([label[b,:] | h0[b,:] | h1[b,:]])
//   blocks [NBX, NBX+NBW): Wb row n = bf16 of the gate-n weight row
// ---------------------------------------------------------------------------
#define NBX  ((BROWS  * (KDIM / 8)) / 256)   // 9216
#define NBW  ((NGATES * (KDIM / 8)) / 256)   // 1440

__global__ __launch_bounds__(256) void pack_all(
    const float* __restrict__ label, const float* __restrict__ chh,
    const float* __restrict__ Wi, const float* __restrict__ Wo,
    const float* __restrict__ Wu, const float* __restrict__ Wfl,
    const float* __restrict__ Wfs,
    short* __restrict__ xb, short* __restrict__ Wb)
{
    const int perRow = KDIM / 8;  // 144
    int blk = blockIdx.x;
    const float* src;
    short* dst;
    if (blk < NBX) {
        int tid = blk * 256 + threadIdx.x;
        int b = tid / perRow;
        int d = (tid - b * perRow) * 8;
        if (d < LDIM) {
            src = label + (size_t)b * LDIM + d;
        } else {
            int dd = d - LDIM;
            int k  = dd >> 9;
            int j  = dd & 511;
            src = chh + ((size_t)k * BROWS + b) * HDIM + j;
        }
        dst = xb + (size_t)b * KDIM + d;
    } else {
        int tid = (blk - NBX) * 256 + threadIdx.x;
        int n = tid / perRow;
        int d = (tid - n * perRow) * 8;
        int g = n >> 9, h = n & 511;
        if (g == 0)      src = Wi + (size_t)h * KDIM + d;
        else if (g == 1) src = Wo + (size_t)h * KDIM + d;
        else if (g == 2) src = Wu + (size_t)h * KDIM + d;
        else {
            int k = g - 3;
            if (d < LDIM) {
                src = Wfl + (size_t)h * LDIM + d;
            } else {
                int dd = d - LDIM;
                int j  = dd >> 9;
                int jj = dd & 511;
                src = Wfs + (((size_t)(k * 2 + j) * HDIM + h) * HDIM) + jj;
            }
        }
        dst = Wb + (size_t)n * KDIM + d;
    }
    float4 v0 = *(const float4*)src;
    float4 v1 = *(const float4*)(src + 4);
    bfrag s;
    s[0] = f2bf(v0.x); s[1] = f2bf(v0.y); s[2] = f2bf(v0.z); s[3] = f2bf(v0.w);
    s[4] = f2bf(v1.x); s[5] = f2bf(v1.y); s[6] = f2bf(v1.z); s[7] = f2bf(v1.w);
    *(bfrag*)dst = s;
}

// ---------------------------------------------------------------------------
// gemm_fused: 256(m) x 320(n=5 gates x 64-h-strip) tile, fused LSTM epilogue.
// Round-5 change: ONE barrier per K64-tile (was 4). Per wave between
// barriers: 26 ds_read_b128 + 80 MFMA (B-frags read once per tile, -28% LDS
// reads). Round-4 post-mortem showed 9307 cyc/tile vs a 3100-cyc matrix-pipe
// floor — barrier-lockstep alternation of the LDS and MFMA pipes; this gives
// the compiler a tile-wide region to pipeline reads under MFMAs.
//
// Double-buffer legality with one barrier/tile: stage(t+1) DMAs are issued
// at the START of tile t's body, targeting buf[(t+1)&1], whose last reads
// (tile t-1) all completed before barrier(t-1) (every read is consumed by an
// MFMA preceding that barrier). Tile-end: s_waitcnt vmcnt(0) + s_barrier —
// the 9 DMAs were issued a full tile (~4000 cyc) earlier, so the drain is
// effectively free (counted-in-time rather than counted-in-N).
//
// Swizzle: proven 128B-row XOR scheme (0 conflicts measured in r2/r4):
// staging thread t covers row t>>3, phys 16B slot t&7, global k-seg
// (t&7)^(row&7); reads at kswz = ((quad [+4 for ks=1]) ^ (l16&7))*16.
// LDS: A 2x32 KB + B 2x40 KB = 144 KiB. 1 block/CU, 2 waves/SIMD.
// ---------------------------------------------------------------------------
__global__ __launch_bounds__(512, 2) void gemm_fused(
    const short* __restrict__ A, const short* __restrict__ Wb,
    const float* __restrict__ chc,
    const float* __restrict__ b_i, const float* __restrict__ b_o,
    const float* __restrict__ b_u, const float* __restrict__ fbias,
    float* __restrict__ out)
{
    __shared__ short As[2][16384];   // 2 x 32 KB (256 rows x 128 B)
    __shared__ short Bs[2][20480];   // 2 x 40 KB (320 rows x 128 B)

    const int t    = threadIdx.x;
    const int lane = t & 63;
    const int wave = t >> 6;          // 0..7
    const int wr   = wave >> 2;       // 0..1  (M)
    const int wc   = wave & 3;        // 0..3  (N, 16-col group within h-strip)
    const int quad = lane >> 4;       // 0..3
    const int l16  = lane & 15;

    // XCD chunking (512 % 8 == 0, bijective): XCD c owns m-tiles [8c,8c+8),
    // h-strip fastest -> resident blocks share A-panels (L2-hot).
    const int local = blockIdx.x >> 3;            // 0..63
    const int mT    = (blockIdx.x & 7) * 8 + (local >> 3);
    const int nT    = local & 7;                  // h-strip
    const int mBase = mT * 256;
    const int h0    = nT * 64;

    f32x4 acc[8][5] = {};   // [m-frag][gate]

    // ---- staging: thread t -> row sr = t>>3 (0..63 per DMA), phys 16B slot
    // t&7, sourced from global k-seg (t&7)^(sr&7).
    const int sr  = t >> 3;
    const int ssl = (t & 7) ^ (sr & 7);
    const short* aSrc = A  + (size_t)(mBase + sr) * KDIM + ssl * 8;
    const short* bSrc = Wb + (size_t)(h0    + sr) * KDIM + ssl * 8;   // gate 0
    short* aDst = &As[0][0] + t * 8;      // lane-linear LDS dest
    short* bDst = &Bs[0][0] + t * 8;

    // A quarter q (64 rows), B strip d = gate d (rows d*512+h0+sr of Wb)
#define STAGE_A(q, kt, buf) load_lds16(aSrc + (size_t)(q) * (64 * KDIM) + (kt) * 64, \
                                       aDst + (buf) * 16384 + (q) * 4096)
#define STAGE_B(d, kt, buf) load_lds16(bSrc + (size_t)(d) * (512 * KDIM) + (kt) * 64, \
                                       bDst + (buf) * 20480 + (d) * 4096)
#define STAGE_ALL(kt, buf) do { \
    STAGE_A(0, kt, buf); STAGE_A(1, kt, buf); STAGE_A(2, kt, buf); STAGE_A(3, kt, buf); \
    STAGE_B(0, kt, buf); STAGE_B(1, kt, buf); STAGE_B(2, kt, buf); STAGE_B(3, kt, buf); \
    STAGE_B(4, kt, buf); \
} while (0)

    // ---- fragment-read constants; all of a thread's rows have row&7==l16&7.
    const int kswz0 = ((quad)     ^ (l16 & 7)) << 4;   // ks=0
    const int kswz1 = ((quad + 4) ^ (l16 & 7)) << 4;   // ks=1
    const int aRowB = (wr * 128 + l16) << 7;           // byte offset of row
    const int bRowB = (wc * 16  + l16) << 7;

    // A frag (mi 0..7): rows wr*128 + mi*16 + l16
#define DS_A(buf, mi, ks) (*(const bfrag*)((const char*)(&As[0][0]) + (buf) * 32768 + \
                              aRowB + (mi) * 2048 + ((ks) ? kswz1 : kswz0)))
    // B frag g: rows g*64 + wc*16 + l16
#define DS_B(buf, g, ks) (*(const bfrag*)((const char*)(&Bs[0][0]) + (buf) * 40960 + \
                              (g) * 8192 + bRowB + ((ks) ? kswz1 : kswz0)))

#define MM(af, bfr, mi, g) acc[mi][g] = \
    __builtin_amdgcn_mfma_f32_16x16x32_bf16(af, bfr, acc[mi][g], 0, 0, 0)

// One K64-tile: stage t+1 (optional), then two ks half-blocks of
// {13 ds_read + 40 MFMA} with NO internal barrier — compiler pipelines reads
// under MFMAs via fine-grained lgkmcnt. Tile ends with vmcnt(0) + barrier
// (omitted for the last tile by the caller via END=0).
#define TILE(bufc, kt, DOSTAGE, END) do { \
    if (DOSTAGE) STAGE_ALL((kt) + 1, bufc ^ 1); \
    { \
        bfrag a0 = DS_A(bufc, 0, 0), a1 = DS_A(bufc, 1, 0); \
        bfrag a2 = DS_A(bufc, 2, 0), a3 = DS_A(bufc, 3, 0); \
        bfrag a4 = DS_A(bufc, 4, 0), a5 = DS_A(bufc, 5, 0); \
        bfrag a6 = DS_A(bufc, 6, 0), a7 = DS_A(bufc, 7, 0); \
        bfrag b0 = DS_B(bufc, 0, 0), b1 = DS_B(bufc, 1, 0); \
        bfrag b2 = DS_B(bufc, 2, 0), b3 = DS_B(bufc, 3, 0); \
        bfrag b4 = DS_B(bufc, 4, 0); \
        __builtin_amdgcn_s_setprio(1); \
        MM(a0, b0, 0, 0); MM(a0, b1, 0, 1); MM(a0, b2, 0, 2); MM(a0, b3, 0, 3); MM(a0, b4, 0, 4); \
        MM(a1, b0, 1, 0); MM(a1, b1, 1, 1); MM(a1, b2, 1, 2); MM(a1, b3, 1, 3); MM(a1, b4, 1, 4); \
        MM(a2, b0, 2, 0); MM(a2, b1, 2, 1); MM(a2, b2, 2, 2); MM(a2, b3, 2, 3); MM(a2, b4, 2, 4); \
        MM(a3, b0, 3, 0); MM(a3, b1, 3, 1); MM(a3, b2, 3, 2); MM(a3, b3, 3, 3); MM(a3, b4, 3, 4); \
        MM(a4, b0, 4, 0); MM(a4, b1, 4, 1); MM(a4, b2, 4, 2); MM(a4, b3, 4, 3); MM(a4, b4, 4, 4); \
        MM(a5, b0, 5, 0); MM(a5, b1, 5, 1); MM(a5, b2, 5, 2); MM(a5, b3, 5, 3); MM(a5, b4, 5, 4); \
        MM(a6, b0, 6, 0); MM(a6, b1, 6, 1); MM(a6, b2, 6, 2); MM(a6, b3, 6, 3); MM(a6, b4, 6, 4); \
        MM(a7, b0, 7, 0); MM(a7, b1, 7, 1); MM(a7, b2, 7, 2); MM(a7, b3, 7, 3); MM(a7, b4, 7, 4); \
        __builtin_amdgcn_s_setprio(0); \
    } \
    { \
        bfrag a0 = DS_A(bufc, 0, 1), a1 = DS_A(bufc, 1, 1); \
        bfrag a2 = DS_A(bufc, 2, 1), a3 = DS_A(bufc, 3, 1); \
        bfrag a4 = DS_A(bufc, 4, 1), a5 = DS_A(bufc, 5, 1); \
        bfrag a6 = DS_A(bufc, 6, 1), a7 = DS_A(bufc, 7, 1); \
        bfrag b0 = DS_B(bufc, 0, 1), b1 = DS_B(bufc, 1, 1); \
        bfrag b2 = DS_B(bufc, 2, 1), b3 = DS_B(bufc, 3, 1); \
        bfrag b4 = DS_B(bufc, 4, 1); \
        __builtin_amdgcn_s_setprio(1); \
        MM(a0, b0, 0, 0); MM(a0, b1, 0, 1); MM(a0, b2, 0, 2); MM(a0, b3, 0, 3); MM(a0, b4, 0, 4); \
        MM(a1, b0, 1, 0); MM(a1, b1, 1, 1); MM(a1, b2, 1, 2); MM(a1, b3, 1, 3); MM(a1, b4, 1, 4); \
        MM(a2, b0, 2, 0); MM(a2, b1, 2, 1); MM(a2, b2, 2, 2); MM(a2, b3, 2, 3); MM(a2, b4, 2, 4); \
        MM(a3, b0, 3, 0); MM(a3, b1, 3, 1); MM(a3, b2, 3, 2); MM(a3, b3, 3, 3); MM(a3, b4, 3, 4); \
        MM(a4, b0, 4, 0); MM(a4, b1, 4, 1); MM(a4, b2, 4, 2); MM(a4, b3, 4, 3); MM(a4, b4, 4, 4); \
        MM(a5, b0, 5, 0); MM(a5, b1, 5, 1); MM(a5, b2, 5, 2); MM(a5, b3, 5, 3); MM(a5, b4, 5, 4); \
        MM(a6, b0, 6, 0); MM(a6, b1, 6, 1); MM(a6, b2, 6, 2); MM(a6, b3, 6, 3); MM(a6, b4, 6, 4); \
        MM(a7, b0, 7, 0); MM(a7, b1, 7, 1); MM(a7, b2, 7, 2); MM(a7, b3, 7, 3); MM(a7, b4, 7, 4); \
        __builtin_amdgcn_s_setprio(0); \
    } \
    if (END) { \
        asm volatile("s_waitcnt vmcnt(0)" ::: "memory"); \
        __builtin_amdgcn_s_barrier(); \
    } \
} while (0)

    // ---- prologue: stage tile 0 into buf0
    STAGE_ALL(0, 0);
    asm volatile("s_waitcnt vmcnt(0)" ::: "memory");
    __builtin_amdgcn_s_barrier();

    // tiles 0..15 (stages 1..16), then peeled 16 (stages 17) and 17 (no stage)
#pragma unroll 1
    for (int k2 = 0; k2 < 8; ++k2) {
        TILE(0, 2 * k2,     1, 1);
        TILE(1, 2 * k2 + 1, 1, 1);
    }
    TILE(0, 16, 1, 1);
    TILE(1, 17, 0, 0);

    // ---- fused LSTM epilogue. Lane holds all 5 gate logits (fp32) for
    // h = h0 + wc*16 + l16, rows b = mBase + wr*128 + mi*16 + quad*4 + r.
    const int h = h0 + wc * 16 + l16;
    const float bi = b_i[h], bo = b_o[h], bu = b_u[h], fb = fbias[h];
    const float* chc1 = chc + (size_t)BROWS * HDIM;
    float* out2 = out + (size_t)BROWS * HDIM;

#pragma unroll
    for (int mi = 0; mi < 8; ++mi) {
        const int row0 = mBase + wr * 128 + mi * 16 + quad * 4;
#pragma unroll
        for (int r = 0; r < 4; ++r) {
            const size_t idx = (size_t)(row0 + r) * HDIM + h;
            float ig = fast_sigmoid(acc[mi][0][r] + bi);
            float og = fast_sigmoid(acc[mi][1][r] + bo);
            float uu = fast_tanh(acc[mi][2][r] + bu);
            float f0 = fast_sigmoid(acc[mi][3][r]);
            float f1 = fast_sigmoid(acc[mi][4][r]);
            float c0 = chc[idx];
            float c1 = chc1[idx];
            float ncell = ig * uu + f0 * c0 + f1 * c1 + fb * (c0 + c1);
            out[idx]  = ncell;
            out2[idx] = fast_tanh(og * ncell);
        }
    }
#undef TILE
#undef MM
#undef DS_A
#undef DS_B
#undef STAGE_ALL
#undef STAGE_A
#undef STAGE_B
}

// ---------------------------------------------------------------------------
extern "C" void kernel_launch(void* const* d_in, const int* in_sizes, int n_in,
                              void* d_out, int out_size, void* d_ws, size_t ws_size,
                              hipStream_t stream) {
    const float* label = (const float*)d_in[0];
    const float* chh   = (const float*)d_in[1];
    const float* chc   = (const float*)d_in[2];
    const float* W_i   = (const float*)d_in[3];
    const float* b_i   = (const float*)d_in[4];
    const float* W_o   = (const float*)d_in[5];
    const float* b_o   = (const float*)d_in[6];
    const float* W_u   = (const float*)d_in[7];
    const float* b_u   = (const float*)d_in[8];
    const float* W_fl  = (const float*)d_in[9];
    const float* W_fs  = (const float*)d_in[10];
    const float* fbias = (const float*)d_in[11];
    float* out = (float*)d_out;

    char* ws = (char*)d_ws;
    short* xb = (short*)ws;                    // B x K bf16
    short* Wb = (short*)(ws + XB_BYTES);       // 2560 x K bf16

    pack_all<<<NBX + NBW, 256, 0, stream>>>(label, chh, W_i, W_o, W_u, W_fl, W_fs, xb, Wb);

    // 64 m-tiles x 8 h-strips = 512 blocks (2.0 rounds of 256 CUs), 512 thr
    gemm_fused<<<dim3(512), 512, 0, stream>>>(xb, Wb, chc, b_i, b_o, b_u, fbias, out);
}